// Round 6
// baseline (21627.194 us; speedup 1.0000x reference)
//
#include <hip/hip_runtime.h>

// SlotAttention: B=32, NF=16, N=192, D=256, S=21, 3 iters/frame.
// ROUND 12: == R11 (passed, absmax 0.875) with the REAL occupancy fix:
// amdgpu_waves_per_eu(4,4) pins the compiler's occupancy target to exactly
// 4 waves/EU -> VGPR budget 512/4 = 128. R10/R11's launch_bounds only set a
// MINIMUM (heuristic still targeted 8/EU -> 64 VGPR -> 434MB spill traffic).

typedef _Float16 f16;

__device__ __align__(16) float g_wkT[65536];  // WkT[d][dd] = Wk[dd][d], fp32

__device__ inline float wredsum(float v) {
#pragma unroll
  for (int m = 32; m > 0; m >>= 1) v += __shfl_xor(v, m, 64);
  return v;
}
__device__ inline float fsigmoid(float x) { return 1.f / (1.f + __expf(-x)); }
__device__ inline float ftanh(float x) {
  float ax = fabsf(x);
  float e = __expf(-2.f * ax);
  return copysignf((1.f - e) / (1.f + e), x);
}

__global__ __launch_bounds__(1024) void k_prep(const float* __restrict__ Wk) {
  int t = blockIdx.x * 1024 + threadIdx.x;  // grid 64*1024 = 65536 exactly
  g_wkT[t] = Wk[((t & 255) << 8) + (t >> 8)];
}

__global__ __attribute__((amdgpu_flat_work_group_size(1024, 1024),
                          amdgpu_waves_per_eu(4, 4))) void k_all(
    const float* __restrict__ x, const float* __restrict__ noise,
    const float* __restrict__ mu, const float* __restrict__ sigma,
    const float* __restrict__ Wq, const float* __restrict__ bq,
    const float* __restrict__ bk,
    const float* __restrict__ Wv, const float* __restrict__ bv,
    const float* __restrict__ W1, const float* __restrict__ b1,
    const float* __restrict__ W2, const float* __restrict__ b2,
    const float* __restrict__ Wih, const float* __restrict__ bih,
    const float* __restrict__ Whh, const float* __restrict__ bhh,
    const float* __restrict__ g_in, const float* __restrict__ be_in,
    const float* __restrict__ g_sl, const float* __restrict__ be_sl,
    const float* __restrict__ g_ff, const float* __restrict__ be_ff,
    float* __restrict__ out_slots, float* __restrict__ out_attn) {
  __shared__ f16 LX[256 * 193];     // lnx column-major: LX[k*193 + j]   98,816 B
  __shared__ float SL[21 * 256];    // slots fp32                        21,504 B
  __shared__ float A[21 * 256];     // lnS / qk / P / h / ffa            21,504 B
  __shared__ float Bf[21 * 256];    // q / dots / attn / upd / lnH      21,504 B
  __shared__ float qb[21], rsum[21];

  const int b = blockIdx.x;
  const int tid = threadIdx.x;
  const int w = tid >> 6, lane = tid & 63;
  const int d = tid & 255;           // owned output column for streamed GEMMs
  const int q4 = tid >> 8;           // row-quarter 0..3
  const int i0 = q4 * 5 + (q4 > 0 ? 1 : 0);   // 0,6,11,16
  const int ni = (q4 == 0) ? 6 : 5;           // 6,5,5,5

  // ---- init slots: mu + sigma*noise ----
  for (int i = tid; i < 21 * 256; i += 1024) {
    int s = i >> 8, dd = i & 255;
    SL[i] = mu[dd] + sigma[dd] * noise[((size_t)b * 21 + s) * 256 + dd];
  }
  __syncthreads();

  float hreg[6];
#pragma unroll
  for (int ii = 0; ii < 6; ii++) hreg[ii] = 0.f;

  for (int f = 0; f < 16; ++f) {
    const float* xf = x + ((size_t)(b * 16 + f)) * 192 * 256;
    // ---- frame LN -> LX (column-major, f16) ----
    for (int rr = 0; rr < 12; rr++) {
      int row = w + rr * 16;  // 0..191
      float4 xv = *(const float4*)(xf + row * 256 + lane * 4);
      float m = wredsum(xv.x + xv.y + xv.z + xv.w) * (1.f / 256.f);
      float d0 = xv.x - m, d1 = xv.y - m, d2 = xv.z - m, d3 = xv.w - m;
      float q2 = wredsum(d0 * d0 + d1 * d1 + d2 * d2 + d3 * d3);
      float rs = 1.f / sqrtf(q2 * (1.f / 256.f) + 1e-5f);
      int c = lane * 4;
      LX[(c + 0) * 193 + row] = (f16)(d0 * rs * g_in[c + 0] + be_in[c + 0]);
      LX[(c + 1) * 193 + row] = (f16)(d1 * rs * g_in[c + 1] + be_in[c + 1]);
      LX[(c + 2) * 193 + row] = (f16)(d2 * rs * g_in[c + 2] + be_in[c + 2]);
      LX[(c + 3) * 193 + row] = (f16)(d3 * rs * g_in[c + 3] + be_in[c + 3]);
    }
    __syncthreads();

    for (int it = 0; it < 3; ++it) {
      // ---- P1: lnS = LN(SL) -> A ----
#pragma unroll
      for (int rr = 0; rr < 2; rr++) {
        int row = w + rr * 16;
        if (row < 21) {
          float4 xv = *(const float4*)(SL + row * 256 + lane * 4);
          float m = wredsum(xv.x + xv.y + xv.z + xv.w) * (1.f / 256.f);
          float d0 = xv.x - m, d1 = xv.y - m, d2 = xv.z - m, d3 = xv.w - m;
          float q2 = wredsum(d0 * d0 + d1 * d1 + d2 * d2 + d3 * d3);
          float rs = 1.f / sqrtf(q2 * (1.f / 256.f) + 1e-5f);
          int c = lane * 4;
          A[row * 256 + c + 0] = d0 * rs * g_sl[c + 0] + be_sl[c + 0];
          A[row * 256 + c + 1] = d1 * rs * g_sl[c + 1] + be_sl[c + 1];
          A[row * 256 + c + 2] = d2 * rs * g_sl[c + 2] + be_sl[c + 2];
          A[row * 256 + c + 3] = d3 * rs * g_sl[c + 3] + be_sl[c + 3];
        }
      }
      __syncthreads();
      // ---- P2: q = lnS @ Wq^T + bq -> Bf ----
      {
        float acc[6] = {0.f, 0.f, 0.f, 0.f, 0.f, 0.f};
        for (int k = 0; k < 256; k += 4) {
          float4 w4 = *(const float4*)(Wq + (size_t)d * 256 + k);
#pragma unroll
          for (int ii = 0; ii < 6; ii++)
            if (ii < ni) {
              float4 av = *(const float4*)(A + (i0 + ii) * 256 + k);
              acc[ii] += av.x * w4.x + av.y * w4.y + av.z * w4.z + av.w * w4.w;
            }
        }
        float bb = bq[d];
#pragma unroll
        for (int ii = 0; ii < 6; ii++)
          if (ii < ni) Bf[(i0 + ii) * 256 + d] = acc[ii] + bb;
      }
      __syncthreads();
      // ---- P3: qk = q @ Wk (WkT rows contiguous) -> A ; qb[i] = q[i]·bk ----
      {
        float acc[6] = {0.f, 0.f, 0.f, 0.f, 0.f, 0.f};
        for (int k = 0; k < 256; k += 4) {
          float4 w4 = *(const float4*)(g_wkT + (size_t)d * 256 + k);
#pragma unroll
          for (int ii = 0; ii < 6; ii++)
            if (ii < ni) {
              float4 qv = *(const float4*)(Bf + (i0 + ii) * 256 + k);
              acc[ii] += qv.x * w4.x + qv.y * w4.y + qv.z * w4.z + qv.w * w4.w;
            }
        }
#pragma unroll
        for (int ii = 0; ii < 6; ii++)
          if (ii < ni) A[(i0 + ii) * 256 + d] = acc[ii];
        if (tid < 336) {  // 21 rows x 16 partials, shfl within 16-thread groups
          int i = tid >> 4, p = tid & 15;
          const float* qrow = Bf + i * 256 + p * 16;
          float s = 0.f;
#pragma unroll
          for (int t2 = 0; t2 < 16; t2++) s += qrow[t2] * bk[p * 16 + t2];
          s += __shfl_xor(s, 1, 64);
          s += __shfl_xor(s, 2, 64);
          s += __shfl_xor(s, 4, 64);
          s += __shfl_xor(s, 8, 64);
          if (p == 0) qb[i] = s;
        }
      }
      __syncthreads();
      // ---- P4: dots = (qk·lnx^T + qb)*scale -> Bf ----
      if (tid < 1008) {  // 21 rows x 48 j-quads
        int i = tid / 48;
        int j = (tid - i * 48) * 4;
        float s0 = 0.f, s1 = 0.f, s2 = 0.f, s3 = 0.f;
        const float* arow = A + i * 256;
        for (int k = 0; k < 256; k += 4) {
          float4 a4 = *(const float4*)(arow + k);
#pragma unroll
          for (int t = 0; t < 4; t++) {
            float av = (t == 0) ? a4.x : (t == 1) ? a4.y : (t == 2) ? a4.z : a4.w;
            const f16* lp = LX + (k + t) * 193 + j;
            s0 += av * (float)lp[0];
            s1 += av * (float)lp[1];
            s2 += av * (float)lp[2];
            s3 += av * (float)lp[3];
          }
        }
        float qbi = qb[i];
        Bf[i * 256 + j + 0] = (s0 + qbi) * 0.0625f;
        Bf[i * 256 + j + 1] = (s1 + qbi) * 0.0625f;
        Bf[i * 256 + j + 2] = (s2 + qbi) * 0.0625f;
        Bf[i * 256 + j + 3] = (s3 + qbi) * 0.0625f;
      }
      __syncthreads();
      // ---- P5a: softmax over slots per column + EPS ----
      if (tid < 192) {
        int j = tid;
        float mx = -1e30f;
#pragma unroll
        for (int i = 0; i < 21; i++) mx = fmaxf(mx, Bf[i * 256 + j]);
        float e[21], sum = 0.f;
#pragma unroll
        for (int i = 0; i < 21; i++) { e[i] = __expf(Bf[i * 256 + j] - mx); sum += e[i]; }
        float inv = 1.f / sum;
#pragma unroll
        for (int i = 0; i < 21; i++) Bf[i * 256 + j] = e[i] * inv + 1e-8f;
      }
      __syncthreads();
      // ---- P5b: row sums over N ----
#pragma unroll
      for (int rr = 0; rr < 2; rr++) {
        int i = w + rr * 16;
        if (i < 21) {
          float s = Bf[i * 256 + lane] + Bf[i * 256 + lane + 64] + Bf[i * 256 + lane + 128];
          s = wredsum(s);
          if (lane == 0) rsum[i] = s;
        }
      }
      __syncthreads();
      // ---- P5c: attn = ao/rsum in-place ; emit attn_ori on it==2 ----
      {
        float* oa = out_attn + ((size_t)(b * 16 + f)) * 4032;
        for (int idx = tid; idx < 4032; idx += 1024) {
          int i = idx / 192, j = idx - i * 192;
          float ao = Bf[i * 256 + j];
          if (it == 2) oa[idx] = ao;
          Bf[i * 256 + j] = ao / rsum[i];
        }
      }
      __syncthreads();
      // ---- P6: P = attn @ lnx -> A  (reduce over j=192) ----
      {
        float acc[6] = {0.f, 0.f, 0.f, 0.f, 0.f, 0.f};
        for (int j = 0; j < 192; j += 4) {
          const f16* lp = LX + d * 193 + j;
          float l0 = (float)lp[0], l1 = (float)lp[1], l2 = (float)lp[2], l3 = (float)lp[3];
#pragma unroll
          for (int ii = 0; ii < 6; ii++)
            if (ii < ni) {
              float4 at = *(const float4*)(Bf + (i0 + ii) * 256 + j);
              acc[ii] += at.x * l0 + at.y * l1 + at.z * l2 + at.w * l3;
            }
        }
#pragma unroll
        for (int ii = 0; ii < 6; ii++)
          if (ii < ni) A[(i0 + ii) * 256 + d] = acc[ii];
      }
      __syncthreads();
      // ---- P7: upd = P @ Wv^T + bv -> Bf ----
      {
        float acc[6] = {0.f, 0.f, 0.f, 0.f, 0.f, 0.f};
        for (int k = 0; k < 256; k += 4) {
          float4 w4 = *(const float4*)(Wv + (size_t)d * 256 + k);
#pragma unroll
          for (int ii = 0; ii < 6; ii++)
            if (ii < ni) {
              float4 pv = *(const float4*)(A + (i0 + ii) * 256 + k);
              acc[ii] += pv.x * w4.x + pv.y * w4.y + pv.z * w4.z + pv.w * w4.w;
            }
        }
        float bb = bv[d];
#pragma unroll
        for (int ii = 0; ii < 6; ii++)
          if (ii < ni) Bf[(i0 + ii) * 256 + d] = acc[ii] + bb;
      }
      __syncthreads();
      // ---- P8: GRU(upd=Bf, slots=SL) -> hreg, A := h ----
      {
        float aR[6] = {0.f, 0.f, 0.f, 0.f, 0.f, 0.f};
        float aZ[6] = {0.f, 0.f, 0.f, 0.f, 0.f, 0.f};
        float aNi[6] = {0.f, 0.f, 0.f, 0.f, 0.f, 0.f};
        float aNh[6] = {0.f, 0.f, 0.f, 0.f, 0.f, 0.f};
        for (int k = 0; k < 256; k += 4) {
          float4 wr4 = *(const float4*)(Wih + (size_t)d * 256 + k);
          float4 wz4 = *(const float4*)(Wih + (size_t)(256 + d) * 256 + k);
          float4 wn4 = *(const float4*)(Wih + (size_t)(512 + d) * 256 + k);
          float4 vr4 = *(const float4*)(Whh + (size_t)d * 256 + k);
          float4 vz4 = *(const float4*)(Whh + (size_t)(256 + d) * 256 + k);
          float4 vn4 = *(const float4*)(Whh + (size_t)(512 + d) * 256 + k);
#pragma unroll
          for (int ii = 0; ii < 6; ii++)
            if (ii < ni) {
              float4 u4 = *(const float4*)(Bf + (i0 + ii) * 256 + k);
              float4 s4 = *(const float4*)(SL + (i0 + ii) * 256 + k);
              aR[ii] += u4.x * wr4.x + u4.y * wr4.y + u4.z * wr4.z + u4.w * wr4.w
                      + s4.x * vr4.x + s4.y * vr4.y + s4.z * vr4.z + s4.w * vr4.w;
              aZ[ii] += u4.x * wz4.x + u4.y * wz4.y + u4.z * wz4.z + u4.w * wz4.w
                      + s4.x * vz4.x + s4.y * vz4.y + s4.z * vz4.z + s4.w * vz4.w;
              aNi[ii] += u4.x * wn4.x + u4.y * wn4.y + u4.z * wn4.z + u4.w * wn4.w;
              aNh[ii] += s4.x * vn4.x + s4.y * vn4.y + s4.z * vn4.z + s4.w * vn4.w;
            }
        }
        float bir = bih[d], biz = bih[256 + d], bin = bih[512 + d];
        float bhr = bhh[d], bhz = bhh[256 + d], bhn = bhh[512 + d];
#pragma unroll
        for (int ii = 0; ii < 6; ii++)
          if (ii < ni) {
            float r = fsigmoid(aR[ii] + bir + bhr);
            float z = fsigmoid(aZ[ii] + biz + bhz);
            float n = ftanh(aNi[ii] + bin + r * (aNh[ii] + bhn));
            float h = (1.f - z) * n + z * SL[(i0 + ii) * 256 + d];
            hreg[ii] = h;
            A[(i0 + ii) * 256 + d] = h;
          }
      }
      __syncthreads();
      // ---- P9: lnH = LN(A) -> Bf ----
#pragma unroll
      for (int rr = 0; rr < 2; rr++) {
        int row = w + rr * 16;
        if (row < 21) {
          float4 xv = *(const float4*)(A + row * 256 + lane * 4);
          float m = wredsum(xv.x + xv.y + xv.z + xv.w) * (1.f / 256.f);
          float d0 = xv.x - m, d1 = xv.y - m, d2 = xv.z - m, d3 = xv.w - m;
          float q2 = wredsum(d0 * d0 + d1 * d1 + d2 * d2 + d3 * d3);
          float rs = 1.f / sqrtf(q2 * (1.f / 256.f) + 1e-5f);
          int c = lane * 4;
          Bf[row * 256 + c + 0] = d0 * rs * g_ff[c + 0] + be_ff[c + 0];
          Bf[row * 256 + c + 1] = d1 * rs * g_ff[c + 1] + be_ff[c + 1];
          Bf[row * 256 + c + 2] = d2 * rs * g_ff[c + 2] + be_ff[c + 2];
          Bf[row * 256 + c + 3] = d3 * rs * g_ff[c + 3] + be_ff[c + 3];
        }
      }
      __syncthreads();
      // ---- P10: ffa = relu(lnH @ W1^T + b1) -> A ----
      {
        float acc[6] = {0.f, 0.f, 0.f, 0.f, 0.f, 0.f};
        for (int k = 0; k < 256; k += 4) {
          float4 w4 = *(const float4*)(W1 + (size_t)d * 256 + k);
#pragma unroll
          for (int ii = 0; ii < 6; ii++)
            if (ii < ni) {
              float4 lv = *(const float4*)(Bf + (i0 + ii) * 256 + k);
              acc[ii] += lv.x * w4.x + lv.y * w4.y + lv.z * w4.z + lv.w * w4.w;
            }
        }
        float bb = b1[d];
#pragma unroll
        for (int ii = 0; ii < 6; ii++)
          if (ii < ni) A[(i0 + ii) * 256 + d] = fmaxf(acc[ii] + bb, 0.f);
      }
      __syncthreads();
      // ---- P11: SL = h + ffa @ W2^T + b2 ----
      {
        float acc[6] = {0.f, 0.f, 0.f, 0.f, 0.f, 0.f};
        for (int k = 0; k < 256; k += 4) {
          float4 w4 = *(const float4*)(W2 + (size_t)d * 256 + k);
#pragma unroll
          for (int ii = 0; ii < 6; ii++)
            if (ii < ni) {
              float4 fv = *(const float4*)(A + (i0 + ii) * 256 + k);
              acc[ii] += fv.x * w4.x + fv.y * w4.y + fv.z * w4.z + fv.w * w4.w;
            }
        }
        float bb = b2[d];
#pragma unroll
        for (int ii = 0; ii < 6; ii++)
          if (ii < ni) SL[(i0 + ii) * 256 + d] = hreg[ii] + acc[ii] + bb;
      }
      __syncthreads();
    }
  }
  // ---- output: slots[:, :20, :] ----
  for (int i = tid; i < 20 * 256; i += 1024) {
    int s = i >> 8, dd = i & 255;
    out_slots[((size_t)b * 20 + s) * 256 + dd] = SL[s * 256 + dd];
  }
}

extern "C" void kernel_launch(void* const* d_in, const int* in_sizes, int n_in,
                              void* d_out, int out_size, void* d_ws, size_t ws_size,
                              hipStream_t stream) {
  const float* inputs = (const float*)d_in[0];
  const float* noise = (const float*)d_in[1];
  const float* mu = (const float*)d_in[2];
  const float* sigma = (const float*)d_in[3];
  const float* Wq = (const float*)d_in[4];
  const float* bq = (const float*)d_in[5];
  const float* Wk = (const float*)d_in[6];
  const float* bk = (const float*)d_in[7];
  const float* Wv = (const float*)d_in[8];
  const float* bv = (const float*)d_in[9];
  const float* W1 = (const float*)d_in[10];
  const float* b1 = (const float*)d_in[11];
  const float* W2 = (const float*)d_in[12];
  const float* b2 = (const float*)d_in[13];
  const float* Wih = (const float*)d_in[14];
  const float* bih = (const float*)d_in[15];
  const float* Whh = (const float*)d_in[16];
  const float* bhh = (const float*)d_in[17];
  const float* g_in = (const float*)d_in[18];
  const float* be_in = (const float*)d_in[19];
  const float* g_sl = (const float*)d_in[20];
  const float* be_sl = (const float*)d_in[21];
  const float* g_ff = (const float*)d_in[22];
  const float* be_ff = (const float*)d_in[23];

  float* out_slots = (float*)d_out;
  float* out_attn = out_slots + 32 * 20 * 256;

  k_prep<<<64, 1024, 0, stream>>>(Wk);
  k_all<<<32, 1024, 0, stream>>>(inputs, noise, mu, sigma, Wq, bq, bk, Wv, bv,
                                 W1, b1, W2, b2, Wih, bih, Whh, bhh,
                                 g_in, be_in, g_sl, be_sl, g_ff, be_ff,
                                 out_slots, out_attn);
}

// Round 8
// 10848.737 us; speedup vs baseline: 1.9935x; 1.9935x over previous
//
#include <hip/hip_runtime.h>

// SlotAttention: B=32, NF=16, N=192, D=256, S=21, 3 iters/frame.
// ROUND 14: resubmit of R13 (split-fp32 MFMA; container failed with no test
// output -- full index audit found no OOB; treating as infra flake, one retry).
// Proven 512-thread skeleton (R0: 12.6ms) + 3-term hi/lo f16 MFMA for
// P2,P3,P7,P10,P11,GRU (88% of MACs). Defensive guard added in k_prep.

typedef _Float16 f16;
typedef _Float16 half8 __attribute__((ext_vector_type(8)));
typedef float floatx4 __attribute__((ext_vector_type(4)));

// packed split weights: per (col, k-oct of 8): [hi8 | lo8] as 2 uint4s.
// uint4 offsets: Wq 0 | WkT 16384 | Wv 32768 | W1 49152 | W2 65536
//                | Wih 81920 (768 cols) | Whh 131072 | end 180224  (2.88 MB)
#define WQ_OFF 0
#define WKT_OFF 16384
#define WV_OFF 32768
#define W1_OFF 49152
#define W2_OFF 65536
#define WIH_OFF 81920
#define WHH_OFF 131072
__device__ __align__(16) uint4 g_wpk[180224];

__device__ inline float wredsum(float v) {
#pragma unroll
  for (int m = 32; m > 0; m >>= 1) v += __shfl_xor(v, m, 64);
  return v;
}
__device__ inline float fsigmoid(float x) { return 1.f / (1.f + __expf(-x)); }
__device__ inline float ftanh(float x) {
  float ax = fabsf(x);
  float e = __expf(-2.f * ax);
  return copysignf((1.f - e) / (1.f + e), x);
}

__device__ inline floatx4 mfma16(half8 a, half8 b, floatx4 c) {
  return __builtin_amdgcn_mfma_f32_16x16x32_f16(a, b, c, 0, 0, 0);
}
__device__ inline void zero8(half8& a) {
#pragma unroll
  for (int e = 0; e < 8; e++) a[e] = (f16)0.f;
}
__device__ inline void split8(const float* __restrict__ p, half8& hi, half8& lo) {
  float4 v0 = *(const float4*)p;
  float4 v1 = *(const float4*)(p + 4);
  float vv[8] = {v0.x, v0.y, v0.z, v0.w, v1.x, v1.y, v1.z, v1.w};
#pragma unroll
  for (int e = 0; e < 8; e++) {
    f16 h = (f16)vv[e];
    hi[e] = h;
    lo[e] = (f16)(vv[e] - (float)h);
  }
}

// acc += Ain[21x256] (fp32 LDS) x W[256->256] via 3-term split MFMA.
// wave wv: mt=wv&1 (rows mt*16..+15), n-tiles (wv>>1)*4 + t.
// A-frag: lane l -> row=l&15, k = (l>>4)*8 + e.  B-frag: col=l&15, same k.
__device__ inline void mfma_gemm_acc(const float* __restrict__ Ain, int woff, int tid,
                                     floatx4 acc[4]) {
  const int l = tid & 63, wv = tid >> 6;
  const int mt = wv & 1, ntb = (wv >> 1) * 4, lq = l >> 4, lr = l & 15;
  const int row = mt * 16 + lr;
  const bool rv = row < 21;
  const float* arow = Ain + row * 256;
  for (int ks = 0; ks < 8; ks++) {
    const int k0 = ks * 32 + lq * 8;
    half8 ahi, alo;
    if (rv) split8(arow + k0, ahi, alo);
    else { zero8(ahi); zero8(alo); }
#pragma unroll
    for (int t = 0; t < 4; t++) {
      const int col = (ntb + t) * 16 + lr;
      const uint4* bp = g_wpk + woff + ((col << 5) + (ks << 2) + lq) * 2;
      union { uint4 u; half8 h; } bh, bl;
      bh.u = bp[0]; bl.u = bp[1];
      acc[t] = mfma16(ahi, bh.h, acc[t]);
      acc[t] = mfma16(alo, bh.h, acc[t]);
      acc[t] = mfma16(ahi, bl.h, acc[t]);
    }
  }
}

// C/D layout (m89-verified): col = lane&15, row = (lane>>4)*4 + reg.
__device__ inline void mfma_gemm_store(float* __restrict__ Out, const floatx4 acc[4],
                                       const float* __restrict__ bias, bool relu, int tid) {
  const int l = tid & 63, wv = tid >> 6;
  const int mt = wv & 1, ntb = (wv >> 1) * 4, lq = l >> 4, lr = l & 15;
#pragma unroll
  for (int t = 0; t < 4; t++) {
    const int col = (ntb + t) * 16 + lr;
    const float bb = bias ? bias[col] : 0.f;
#pragma unroll
    for (int r = 0; r < 4; r++) {
      const int i = mt * 16 + lq * 4 + r;
      if (i < 21) {
        float v = acc[t][r] + bb;
        Out[i * 256 + col] = relu ? fmaxf(v, 0.f) : v;
      }
    }
  }
}

// split all 7 weight matrices into f16 hi/lo pairs. 88*1024 = 90112 octs exactly.
__global__ __launch_bounds__(1024) void k_prep(
    const float* __restrict__ Wq, const float* __restrict__ Wk, const float* __restrict__ Wv,
    const float* __restrict__ W1, const float* __restrict__ W2,
    const float* __restrict__ Wih, const float* __restrict__ Whh) {
  int t = blockIdx.x * 1024 + threadIdx.x;
  if (t >= 90112) return;  // defensive
  const float* src;
  int idx;
  bool tr = false;
  if (t < 8192) { src = Wq; idx = t; }
  else if (t < 16384) { src = Wk; idx = t - 8192; tr = true; }
  else if (t < 24576) { src = Wv; idx = t - 16384; }
  else if (t < 32768) { src = W1; idx = t - 24576; }
  else if (t < 40960) { src = W2; idx = t - 32768; }
  else if (t < 65536) { src = Wih; idx = t - 40960; }
  else { src = Whh; idx = t - 65536; }
  int c = idx >> 5, ko = idx & 31;
  union { uint4 u; f16 h[8]; } H, L;
#pragma unroll
  for (int e = 0; e < 8; e++) {
    int k = ko * 8 + e;
    float v = tr ? src[(size_t)k * 256 + c] : src[(size_t)c * 256 + k];
    f16 hi = (f16)v;
    H.h[e] = hi;
    L.h[e] = (f16)(v - (float)hi);
  }
  g_wpk[(size_t)t * 2] = H.u;
  g_wpk[(size_t)t * 2 + 1] = L.u;
}

__global__ __launch_bounds__(512) void k_all(
    const float* __restrict__ x, const float* __restrict__ noise,
    const float* __restrict__ mu, const float* __restrict__ sigma,
    const float* __restrict__ bq, const float* __restrict__ bk,
    const float* __restrict__ bv, const float* __restrict__ b1,
    const float* __restrict__ b2, const float* __restrict__ bih,
    const float* __restrict__ bhh,
    const float* __restrict__ g_in, const float* __restrict__ be_in,
    const float* __restrict__ g_sl, const float* __restrict__ be_sl,
    const float* __restrict__ g_ff, const float* __restrict__ be_ff,
    float* __restrict__ out_slots, float* __restrict__ out_attn) {
  __shared__ f16 LX[256 * 193];     // lnx column-major: LX[k*193 + j]   98,816 B
  __shared__ alignas(16) float SL[21 * 256];    // slots fp32            21,504 B
  __shared__ alignas(16) float A[21 * 256];     // lnS / qk / P / h / ffa
  __shared__ alignas(16) float Bf[21 * 256];    // q / dots / attn / upd / lnH
  __shared__ float qb[21], rsum[21];

  const int b = blockIdx.x;
  const int tid = threadIdx.x;
  const int w = tid >> 6, lane = tid & 63;
  const int d = tid & 255;        // owned output column (P6)
  const int half = tid >> 8;      // 0 or 1
  const int i0 = half * 11;       // rows 0..10 / 11..20
  const int ni = 11 - half;       // 11 / 10
  const floatx4 vzero = {0.f, 0.f, 0.f, 0.f};

  // ---- init slots: mu + sigma*noise ----
  for (int i = tid; i < 21 * 256; i += 512) {
    int s = i >> 8, dd = i & 255;
    SL[i] = mu[dd] + sigma[dd] * noise[((size_t)b * 21 + s) * 256 + dd];
  }
  __syncthreads();

  for (int f = 0; f < 16; ++f) {
    const float* xf = x + ((size_t)(b * 16 + f)) * 192 * 256;
    // ---- frame LN -> LX (column-major, f16) ----
    for (int rr = 0; rr < 24; rr++) {
      int row = w + rr * 8;  // 0..191
      float4 xv = *(const float4*)(xf + row * 256 + lane * 4);
      float m = wredsum(xv.x + xv.y + xv.z + xv.w) * (1.f / 256.f);
      float d0 = xv.x - m, d1 = xv.y - m, d2 = xv.z - m, d3 = xv.w - m;
      float q2 = wredsum(d0 * d0 + d1 * d1 + d2 * d2 + d3 * d3);
      float rs = 1.f / sqrtf(q2 * (1.f / 256.f) + 1e-5f);
      int c = lane * 4;
      LX[(c + 0) * 193 + row] = (f16)(d0 * rs * g_in[c + 0] + be_in[c + 0]);
      LX[(c + 1) * 193 + row] = (f16)(d1 * rs * g_in[c + 1] + be_in[c + 1]);
      LX[(c + 2) * 193 + row] = (f16)(d2 * rs * g_in[c + 2] + be_in[c + 2]);
      LX[(c + 3) * 193 + row] = (f16)(d3 * rs * g_in[c + 3] + be_in[c + 3]);
    }
    __syncthreads();

    for (int it = 0; it < 3; ++it) {
      // ---- P1: lnS = LN(SL) -> A ----
#pragma unroll
      for (int rr = 0; rr < 3; rr++) {
        int row = w + rr * 8;
        if (row < 21) {
          float4 xv = *(const float4*)(SL + row * 256 + lane * 4);
          float m = wredsum(xv.x + xv.y + xv.z + xv.w) * (1.f / 256.f);
          float d0 = xv.x - m, d1 = xv.y - m, d2 = xv.z - m, d3 = xv.w - m;
          float q2 = wredsum(d0 * d0 + d1 * d1 + d2 * d2 + d3 * d3);
          float rs = 1.f / sqrtf(q2 * (1.f / 256.f) + 1e-5f);
          int c = lane * 4;
          A[row * 256 + c + 0] = d0 * rs * g_sl[c + 0] + be_sl[c + 0];
          A[row * 256 + c + 1] = d1 * rs * g_sl[c + 1] + be_sl[c + 1];
          A[row * 256 + c + 2] = d2 * rs * g_sl[c + 2] + be_sl[c + 2];
          A[row * 256 + c + 3] = d3 * rs * g_sl[c + 3] + be_sl[c + 3];
        }
      }
      __syncthreads();
      // ---- P2: q = lnS @ Wq^T + bq -> Bf (MFMA) ----
      {
        floatx4 acc[4] = {vzero, vzero, vzero, vzero};
        mfma_gemm_acc(A, WQ_OFF, tid, acc);
        mfma_gemm_store(Bf, acc, bq, false, tid);
      }
      __syncthreads();
      // ---- P3: qk = q @ Wk -> A (MFMA, WkT) ; qb[i] = q[i]·bk ----
      {
        floatx4 acc[4] = {vzero, vzero, vzero, vzero};
        mfma_gemm_acc(Bf, WKT_OFF, tid, acc);
        mfma_gemm_store(A, acc, nullptr, false, tid);
        if (tid < 336) {  // 21 rows x 16 partials
          int i = tid >> 4, p = tid & 15;
          const float* qrow = Bf + i * 256 + p * 16;
          float s = 0.f;
#pragma unroll
          for (int t2 = 0; t2 < 16; t2++) s += qrow[t2] * bk[p * 16 + t2];
          s += __shfl_xor(s, 1, 64);
          s += __shfl_xor(s, 2, 64);
          s += __shfl_xor(s, 4, 64);
          s += __shfl_xor(s, 8, 64);
          if (p == 0) qb[i] = s;
        }
      }
      __syncthreads();
      // ---- P4: dots = (qk·lnx^T + qb)*scale -> Bf ----
      for (int c = 0; c < 8; c++) {
        int o = tid + (c << 9);
        if (o < 4032) {
          int i = o / 192, j = o - i * 192;
          float s = 0.f;
          for (int k = 0; k < 256; k += 4) {
            float4 q4 = *(const float4*)(A + i * 256 + k);
            s += q4.x * (float)LX[(k + 0) * 193 + j];
            s += q4.y * (float)LX[(k + 1) * 193 + j];
            s += q4.z * (float)LX[(k + 2) * 193 + j];
            s += q4.w * (float)LX[(k + 3) * 193 + j];
          }
          Bf[i * 256 + j] = (s + qb[i]) * 0.0625f;
        }
      }
      __syncthreads();
      // ---- P5a: softmax over slots per column + EPS ----
      if (tid < 192) {
        int j = tid;
        float mx = -1e30f;
#pragma unroll
        for (int i = 0; i < 21; i++) mx = fmaxf(mx, Bf[i * 256 + j]);
        float e[21], sum = 0.f;
#pragma unroll
        for (int i = 0; i < 21; i++) { e[i] = __expf(Bf[i * 256 + j] - mx); sum += e[i]; }
        float inv = 1.f / sum;
#pragma unroll
        for (int i = 0; i < 21; i++) Bf[i * 256 + j] = e[i] * inv + 1e-8f;
      }
      __syncthreads();
      // ---- P5b: row sums over N ----
#pragma unroll
      for (int q3 = 0; q3 < 3; q3++) {
        int i = w * 3 + q3;
        if (i < 21) {
          float s = Bf[i * 256 + lane] + Bf[i * 256 + lane + 64] + Bf[i * 256 + lane + 128];
          s = wredsum(s);
          if (lane == 0) rsum[i] = s;
        }
      }
      __syncthreads();
      // ---- P5c: attn = ao/rsum ; emit attn_ori on it==2 ----
      {
        float* oa = out_attn + ((size_t)(b * 16 + f)) * 4032;
        for (int idx = tid; idx < 4032; idx += 512) {
          int i = idx / 192, j = idx - i * 192;
          float ao = Bf[i * 256 + j];
          if (it == 2) oa[idx] = ao;
          Bf[i * 256 + j] = ao / rsum[i];
        }
      }
      __syncthreads();
      // ---- P6: P = attn @ lnx -> A (reduce over j=192) ----
      {
        float acc[11];
#pragma unroll
        for (int ii = 0; ii < 11; ii++) acc[ii] = 0.f;
        for (int j = 0; j < 192; j += 4) {
          float l0 = (float)LX[d * 193 + j + 0];
          float l1 = (float)LX[d * 193 + j + 1];
          float l2 = (float)LX[d * 193 + j + 2];
          float l3 = (float)LX[d * 193 + j + 3];
#pragma unroll
          for (int ii = 0; ii < 11; ii++)
            if (ii < ni) {
              float4 at = *(const float4*)(Bf + (i0 + ii) * 256 + j);
              acc[ii] += at.x * l0 + at.y * l1 + at.z * l2 + at.w * l3;
            }
        }
#pragma unroll
        for (int ii = 0; ii < 11; ii++)
          if (ii < ni) A[(i0 + ii) * 256 + d] = acc[ii];
      }
      __syncthreads();
      // ---- P7: upd = P @ Wv^T + bv -> Bf (MFMA) ----
      {
        floatx4 acc[4] = {vzero, vzero, vzero, vzero};
        mfma_gemm_acc(A, WV_OFF, tid, acc);
        mfma_gemm_store(Bf, acc, bv, false, tid);
      }
      __syncthreads();
      // ---- P8: GRU(upd=Bf, slots=SL) -> A := h (MFMA, ih/hh separate accs) ----
      {
        const int l = tid & 63, wv = tid >> 6;
        const int mt = wv & 1, dtb = (wv >> 1) * 4, lq = l >> 4, lr = l & 15;
        const int row = mt * 16 + lr;
        const bool rv = row < 21;
        const float* urow = Bf + row * 256;
        const float* srow = SL + row * 256;
        for (int p = 0; p < 2; p++) {
          floatx4 aih[2][3], ahh[2][3];
#pragma unroll
          for (int gi = 0; gi < 2; gi++)
#pragma unroll
            for (int g = 0; g < 3; g++) { aih[gi][g] = vzero; ahh[gi][g] = vzero; }
          for (int ks = 0; ks < 8; ks++) {
            const int k0 = ks * 32 + lq * 8;
            half8 uhi, ulo, shi, slo;
            if (rv) { split8(urow + k0, uhi, ulo); split8(srow + k0, shi, slo); }
            else { zero8(uhi); zero8(ulo); zero8(shi); zero8(slo); }
#pragma unroll
            for (int gi = 0; gi < 2; gi++) {
              const int dt = dtb + p * 2 + gi;
#pragma unroll
              for (int g = 0; g < 3; g++) {
                const int colI = g * 256 + dt * 16 + lr;
                const uint4* bp = g_wpk + WIH_OFF + ((colI << 5) + (ks << 2) + lq) * 2;
                union { uint4 u; half8 h; } bh, bl;
                bh.u = bp[0]; bl.u = bp[1];
                aih[gi][g] = mfma16(uhi, bh.h, aih[gi][g]);
                aih[gi][g] = mfma16(ulo, bh.h, aih[gi][g]);
                aih[gi][g] = mfma16(uhi, bl.h, aih[gi][g]);
                const uint4* bp2 = g_wpk + WHH_OFF + ((colI << 5) + (ks << 2) + lq) * 2;
                bh.u = bp2[0]; bl.u = bp2[1];
                ahh[gi][g] = mfma16(shi, bh.h, ahh[gi][g]);
                ahh[gi][g] = mfma16(slo, bh.h, ahh[gi][g]);
                ahh[gi][g] = mfma16(shi, bl.h, ahh[gi][g]);
              }
            }
          }
#pragma unroll
          for (int gi = 0; gi < 2; gi++) {
            const int dt = dtb + p * 2 + gi;
            const int dd = dt * 16 + lr;
            const float bihr = bih[dd], bihz = bih[256 + dd], bihn = bih[512 + dd];
            const float bhhr = bhh[dd], bhhz = bhh[256 + dd], bhhn = bhh[512 + dd];
#pragma unroll
            for (int r = 0; r < 4; r++) {
              const int i = mt * 16 + lq * 4 + r;
              if (i < 21) {
                float rg = fsigmoid(aih[gi][0][r] + ahh[gi][0][r] + bihr + bhhr);
                float zg = fsigmoid(aih[gi][1][r] + ahh[gi][1][r] + bihz + bhhz);
                float ng = ftanh(aih[gi][2][r] + bihn + rg * (ahh[gi][2][r] + bhhn));
                A[i * 256 + dd] = (1.f - zg) * ng + zg * SL[i * 256 + dd];
              }
            }
          }
        }
      }
      __syncthreads();
      // ---- P9: lnH = LN(A) -> Bf ----
#pragma unroll
      for (int rr = 0; rr < 3; rr++) {
        int row = w + rr * 8;
        if (row < 21) {
          float4 xv = *(const float4*)(A + row * 256 + lane * 4);
          float m = wredsum(xv.x + xv.y + xv.z + xv.w) * (1.f / 256.f);
          float d0 = xv.x - m, d1 = xv.y - m, d2 = xv.z - m, d3 = xv.w - m;
          float q2 = wredsum(d0 * d0 + d1 * d1 + d2 * d2 + d3 * d3);
          float rs = 1.f / sqrtf(q2 * (1.f / 256.f) + 1e-5f);
          int c = lane * 4;
          Bf[row * 256 + c + 0] = d0 * rs * g_ff[c + 0] + be_ff[c + 0];
          Bf[row * 256 + c + 1] = d1 * rs * g_ff[c + 1] + be_ff[c + 1];
          Bf[row * 256 + c + 2] = d2 * rs * g_ff[c + 2] + be_ff[c + 2];
          Bf[row * 256 + c + 3] = d3 * rs * g_ff[c + 3] + be_ff[c + 3];
        }
      }
      __syncthreads();
      // ---- P10: ffa = relu(lnH @ W1^T + b1) -> SL (slots dead after GRU) ----
      {
        floatx4 acc[4] = {vzero, vzero, vzero, vzero};
        mfma_gemm_acc(Bf, W1_OFF, tid, acc);
        mfma_gemm_store(SL, acc, b1, true, tid);
      }
      __syncthreads();
      // ---- P11: SL = h(A) + ffa(SL) @ W2^T + b2 (MFMA; barrier before in-place write) ----
      {
        floatx4 acc[4] = {vzero, vzero, vzero, vzero};
        mfma_gemm_acc(SL, W2_OFF, tid, acc);
        __syncthreads();
        const int l = tid & 63, wv = tid >> 6;
        const int mt = wv & 1, ntb = (wv >> 1) * 4, lq = l >> 4, lr = l & 15;
#pragma unroll
        for (int t = 0; t < 4; t++) {
          const int col = (ntb + t) * 16 + lr;
          const float bb = b2[col];
#pragma unroll
          for (int r = 0; r < 4; r++) {
            const int i = mt * 16 + lq * 4 + r;
            if (i < 21) SL[i * 256 + col] = A[i * 256 + col] + acc[t][r] + bb;
          }
        }
      }
      __syncthreads();
    }
  }
  // ---- output: slots[:, :20, :] ----
  for (int i = tid; i < 20 * 256; i += 512) {
    int s = i >> 8, dd = i & 255;
    out_slots[((size_t)b * 20 + s) * 256 + dd] = SL[s * 256 + dd];
  }
}

extern "C" void kernel_launch(void* const* d_in, const int* in_sizes, int n_in,
                              void* d_out, int out_size, void* d_ws, size_t ws_size,
                              hipStream_t stream) {
  const float* inputs = (const float*)d_in[0];
  const float* noise = (const float*)d_in[1];
  const float* mu = (const float*)d_in[2];
  const float* sigma = (const float*)d_in[3];
  const float* Wq = (const float*)d_in[4];
  const float* bq = (const float*)d_in[5];
  const float* Wk = (const float*)d_in[6];
  const float* bk = (const float*)d_in[7];
  const float* Wv = (const float*)d_in[8];
  const float* bv = (const float*)d_in[9];
  const float* W1 = (const float*)d_in[10];
  const float* b1 = (const float*)d_in[11];
  const float* W2 = (const float*)d_in[12];
  const float* b2 = (const float*)d_in[13];
  const float* Wih = (const float*)d_in[14];
  const float* bih = (const float*)d_in[15];
  const float* Whh = (const float*)d_in[16];
  const float* bhh = (const float*)d_in[17];
  const float* g_in = (const float*)d_in[18];
  const float* be_in = (const float*)d_in[19];
  const float* g_sl = (const float*)d_in[20];
  const float* be_sl = (const float*)d_in[21];
  const float* g_ff = (const float*)d_in[22];
  const float* be_ff = (const float*)d_in[23];

  float* out_slots = (float*)d_out;
  float* out_attn = out_slots + 32 * 20 * 256;

  k_prep<<<88, 1024, 0, stream>>>(Wq, Wk, Wv, W1, W2, Wih, Whh);
  k_all<<<32, 512, 0, stream>>>(inputs, noise, mu, sigma, bq, bk, bv, b1, b2,
                                bih, bhh, g_in, be_in, g_sl, be_sl, g_ff, be_ff,
                                out_slots, out_attn);
}

// Round 11
// 8948.124 us; speedup vs baseline: 2.4170x; 1.2124x over previous
//
#include <hip/hip_runtime.h>

// SlotAttention: B=32, NF=16, N=192, D=256, S=21, 3 iters/frame.
// ROUND 17: R15 content, LDS fixed by MERGING SL/A/Bf into one buffer (hipcc
// pads each separate __shared__ array to 16B -> 163848; single FBUF -> 163832).
// R15 content: stride-258 conflict-free split reads + P4/P6 on MFMA.

typedef _Float16 f16;
typedef _Float16 half8 __attribute__((ext_vector_type(8)));
typedef float floatx4 __attribute__((ext_vector_type(4)));

#define SSTR 258  // fp32 LDS row stride: mod 32 == 2 -> conflict-free split reads

// packed split weights: per (col, k-oct of 8): [hi8 | lo8] as 2 uint4s.
#define WQ_OFF 0
#define WKT_OFF 16384
#define WV_OFF 32768
#define W1_OFF 49152
#define W2_OFF 65536
#define WIH_OFF 81920
#define WHH_OFF 131072
__device__ __align__(16) uint4 g_wpk[180224];

__device__ inline float wredsum(float v) {
#pragma unroll
  for (int m = 32; m > 0; m >>= 1) v += __shfl_xor(v, m, 64);
  return v;
}
__device__ inline float fsigmoid(float x) { return 1.f / (1.f + __expf(-x)); }
__device__ inline float ftanh(float x) {
  float ax = fabsf(x);
  float e = __expf(-2.f * ax);
  return copysignf((1.f - e) / (1.f + e), x);
}

__device__ inline floatx4 mfma16(half8 a, half8 b, floatx4 c) {
  return __builtin_amdgcn_mfma_f32_16x16x32_f16(a, b, c, 0, 0, 0);
}
__device__ inline void zero8(half8& a) {
#pragma unroll
  for (int e = 0; e < 8; e++) a[e] = (f16)0.f;
}
// 8 fp32 from LDS via 4x 8B-aligned float2 (base row*SSTR + k0, both even)
__device__ inline void split8s(const float* __restrict__ p, half8& hi, half8& lo) {
  float2 a = *(const float2*)(p);
  float2 b = *(const float2*)(p + 2);
  float2 c = *(const float2*)(p + 4);
  float2 d = *(const float2*)(p + 6);
  float vv[8] = {a.x, a.y, b.x, b.y, c.x, c.y, d.x, d.y};
#pragma unroll
  for (int e = 0; e < 8; e++) {
    f16 h = (f16)vv[e];
    hi[e] = h;
    lo[e] = (f16)(vv[e] - (float)h);
  }
}

// acc += Ain[21 x 256 @SSTR] x W via 3-term split MFMA (layout proven in R14).
__device__ inline void mfma_gemm_acc(const float* __restrict__ Ain, int woff, int tid,
                                     floatx4 acc[4]) {
  const int l = tid & 63, wv = tid >> 6;
  const int mt = wv & 1, ntb = (wv >> 1) * 4, lq = l >> 4, lr = l & 15;
  const int row = mt * 16 + lr;
  const bool rv = row < 21;
  const float* arow = Ain + row * SSTR;
  for (int ks = 0; ks < 8; ks++) {
    const int k0 = ks * 32 + lq * 8;
    half8 ahi, alo;
    if (rv) split8s(arow + k0, ahi, alo);
    else { zero8(ahi); zero8(alo); }
#pragma unroll
    for (int t = 0; t < 4; t++) {
      const int col = (ntb + t) * 16 + lr;
      const uint4* bp = g_wpk + woff + ((col << 5) + (ks << 2) + lq) * 2;
      union { uint4 u; half8 h; } bh, bl;
      bh.u = bp[0]; bl.u = bp[1];
      acc[t] = mfma16(ahi, bh.h, acc[t]);
      acc[t] = mfma16(alo, bh.h, acc[t]);
      acc[t] = mfma16(ahi, bl.h, acc[t]);
    }
  }
}

// C/D layout (R14-verified): col = lane&15 tile, row = (lane>>4)*4 + reg.
__device__ inline void mfma_gemm_store(float* __restrict__ Out, const floatx4 acc[4],
                                       const float* __restrict__ bias, bool relu, int tid) {
  const int l = tid & 63, wv = tid >> 6;
  const int mt = wv & 1, ntb = (wv >> 1) * 4, lq = l >> 4, lr = l & 15;
#pragma unroll
  for (int t = 0; t < 4; t++) {
    const int col = (ntb + t) * 16 + lr;
    const float bb = bias ? bias[col] : 0.f;
#pragma unroll
    for (int r = 0; r < 4; r++) {
      const int i = mt * 16 + lq * 4 + r;
      if (i < 21) {
        float v = acc[t][r] + bb;
        Out[i * SSTR + col] = relu ? fmaxf(v, 0.f) : v;
      }
    }
  }
}

// split all 7 weight matrices into f16 hi/lo pairs. 88*1024 = 90112 octs exactly.
__global__ __launch_bounds__(1024) void k_prep(
    const float* __restrict__ Wq, const float* __restrict__ Wk, const float* __restrict__ Wv,
    const float* __restrict__ W1, const float* __restrict__ W2,
    const float* __restrict__ Wih, const float* __restrict__ Whh) {
  int t = blockIdx.x * 1024 + threadIdx.x;
  if (t >= 90112) return;
  const float* src;
  int idx;
  bool tr = false;
  if (t < 8192) { src = Wq; idx = t; }
  else if (t < 16384) { src = Wk; idx = t - 8192; tr = true; }
  else if (t < 24576) { src = Wv; idx = t - 16384; }
  else if (t < 32768) { src = W1; idx = t - 24576; }
  else if (t < 40960) { src = W2; idx = t - 32768; }
  else if (t < 65536) { src = Wih; idx = t - 40960; }
  else { src = Whh; idx = t - 65536; }
  int c = idx >> 5, ko = idx & 31;
  union { uint4 u; f16 h[8]; } H, L;
#pragma unroll
  for (int e = 0; e < 8; e++) {
    int k = ko * 8 + e;
    float v = tr ? src[(size_t)k * 256 + c] : src[(size_t)c * 256 + k];
    f16 hi = (f16)v;
    H.h[e] = hi;
    L.h[e] = (f16)(v - (float)hi);
  }
  g_wpk[(size_t)t * 2] = H.u;
  g_wpk[(size_t)t * 2 + 1] = L.u;
}

__global__ __launch_bounds__(512) void k_all(
    const float* __restrict__ x, const float* __restrict__ noise,
    const float* __restrict__ mu, const float* __restrict__ sigma,
    const float* __restrict__ bq, const float* __restrict__ bk,
    const float* __restrict__ bv, const float* __restrict__ b1,
    const float* __restrict__ b2, const float* __restrict__ bih,
    const float* __restrict__ bhh,
    const float* __restrict__ g_in, const float* __restrict__ be_in,
    const float* __restrict__ g_sl, const float* __restrict__ be_sl,
    const float* __restrict__ g_ff, const float* __restrict__ be_ff,
    float* __restrict__ out_slots, float* __restrict__ out_attn) {
  __shared__ f16 LX[256 * 193];                  // 98,816 B
  __shared__ float FBUF[3 * 21 * SSTR];          // 65,016 B -- SL | A | Bf merged
  float* SL = FBUF;                              // pad: A[*+256]=qb, A[*+257]=rsum
  float* A = FBUF + 21 * SSTR;
  float* Bf = FBUF + 2 * 21 * SSTR;

  const int b = blockIdx.x;
  const int tid = threadIdx.x;
  const int w = tid >> 6, lane = tid & 63;
  const floatx4 vzero = {0.f, 0.f, 0.f, 0.f};

  // ---- init slots: mu + sigma*noise ----
  for (int i = tid; i < 21 * 256; i += 512) {
    int s = i >> 8, dd = i & 255;
    SL[s * SSTR + dd] = mu[dd] + sigma[dd] * noise[((size_t)b * 21 + s) * 256 + dd];
  }
  __syncthreads();

  for (int f = 0; f < 16; ++f) {
    const float* xf = x + ((size_t)(b * 16 + f)) * 192 * 256;
    // ---- frame LN -> LX (column-major, f16) ----
    for (int rr = 0; rr < 24; rr++) {
      int row = w + rr * 8;  // 0..191
      float4 xv = *(const float4*)(xf + row * 256 + lane * 4);
      float m = wredsum(xv.x + xv.y + xv.z + xv.w) * (1.f / 256.f);
      float d0 = xv.x - m, d1 = xv.y - m, d2 = xv.z - m, d3 = xv.w - m;
      float q2 = wredsum(d0 * d0 + d1 * d1 + d2 * d2 + d3 * d3);
      float rs = 1.f / sqrtf(q2 * (1.f / 256.f) + 1e-5f);
      int c = lane * 4;
      LX[(c + 0) * 193 + row] = (f16)(d0 * rs * g_in[c + 0] + be_in[c + 0]);
      LX[(c + 1) * 193 + row] = (f16)(d1 * rs * g_in[c + 1] + be_in[c + 1]);
      LX[(c + 2) * 193 + row] = (f16)(d2 * rs * g_in[c + 2] + be_in[c + 2]);
      LX[(c + 3) * 193 + row] = (f16)(d3 * rs * g_in[c + 3] + be_in[c + 3]);
    }
    __syncthreads();

    for (int it = 0; it < 3; ++it) {
      // ---- P1: lnS = LN(SL) -> A ----
#pragma unroll
      for (int rr = 0; rr < 3; rr++) {
        int row = w + rr * 8;
        if (row < 21) {
          const float* sr = SL + row * SSTR + lane * 4;
          float2 xa = *(const float2*)(sr);
          float2 xb = *(const float2*)(sr + 2);
          float m = wredsum(xa.x + xa.y + xb.x + xb.y) * (1.f / 256.f);
          float d0 = xa.x - m, d1 = xa.y - m, d2 = xb.x - m, d3 = xb.y - m;
          float q2 = wredsum(d0 * d0 + d1 * d1 + d2 * d2 + d3 * d3);
          float rs = 1.f / sqrtf(q2 * (1.f / 256.f) + 1e-5f);
          int c = lane * 4;
          A[row * SSTR + c + 0] = d0 * rs * g_sl[c + 0] + be_sl[c + 0];
          A[row * SSTR + c + 1] = d1 * rs * g_sl[c + 1] + be_sl[c + 1];
          A[row * SSTR + c + 2] = d2 * rs * g_sl[c + 2] + be_sl[c + 2];
          A[row * SSTR + c + 3] = d3 * rs * g_sl[c + 3] + be_sl[c + 3];
        }
      }
      __syncthreads();
      // ---- P2: q = lnS @ Wq^T + bq -> Bf (MFMA) ----
      {
        floatx4 acc[4] = {vzero, vzero, vzero, vzero};
        mfma_gemm_acc(A, WQ_OFF, tid, acc);
        mfma_gemm_store(Bf, acc, bq, false, tid);
      }
      __syncthreads();
      // ---- P3: qk = q @ Wk -> A (MFMA, WkT) ; qb[i] -> A pad ----
      {
        floatx4 acc[4] = {vzero, vzero, vzero, vzero};
        mfma_gemm_acc(Bf, WKT_OFF, tid, acc);
        mfma_gemm_store(A, acc, nullptr, false, tid);
        if (tid < 336) {  // 21 rows x 16 partials
          int i = tid >> 4, p = tid & 15;
          const float* qrow = Bf + i * SSTR + p * 16;
          float s = 0.f;
#pragma unroll
          for (int t2 = 0; t2 < 16; t2++) s += qrow[t2] * bk[p * 16 + t2];
          s += __shfl_xor(s, 1, 64);
          s += __shfl_xor(s, 2, 64);
          s += __shfl_xor(s, 4, 64);
          s += __shfl_xor(s, 8, 64);
          if (p == 0) A[i * SSTR + 256] = s;  // qb
        }
      }
      __syncthreads();
      // ---- P4: dots = (qk @ lnx^T + qb)*scale -> Bf (MFMA 2-term, N=192) ----
      {
        const int l = tid & 63, wv = tid >> 6;
        const int mt = wv & 1, jtb = (wv >> 1) * 3, lq = l >> 4, lr = l & 15;
        const int row = mt * 16 + lr;
        const bool rv = row < 21;
        const float* arow = A + row * SSTR;
        floatx4 acc[3] = {vzero, vzero, vzero};
        for (int ks = 0; ks < 8; ks++) {
          const int k0 = ks * 32 + lq * 8;
          half8 ahi, alo;
          if (rv) split8s(arow + k0, ahi, alo);
          else { zero8(ahi); zero8(alo); }
#pragma unroll
          for (int t = 0; t < 3; t++) {
            const int j = (jtb + t) * 16 + lr;
            half8 bfr;
#pragma unroll
            for (int e = 0; e < 8; e++) bfr[e] = LX[(k0 + e) * 193 + j];
            acc[t] = mfma16(ahi, bfr, acc[t]);
            acc[t] = mfma16(alo, bfr, acc[t]);
          }
        }
#pragma unroll
        for (int t = 0; t < 3; t++) {
          const int j = (jtb + t) * 16 + lr;
#pragma unroll
          for (int r = 0; r < 4; r++) {
            const int i = mt * 16 + lq * 4 + r;
            if (i < 21) Bf[i * SSTR + j] = (acc[t][r] + A[i * SSTR + 256]) * 0.0625f;
          }
        }
      }
      __syncthreads();
      // ---- P5a: softmax over slots per column + EPS ----
      if (tid < 192) {
        int j = tid;
        float mx = -1e30f;
#pragma unroll
        for (int i = 0; i < 21; i++) mx = fmaxf(mx, Bf[i * SSTR + j]);
        float e[21], sum = 0.f;
#pragma unroll
        for (int i = 0; i < 21; i++) { e[i] = __expf(Bf[i * SSTR + j] - mx); sum += e[i]; }
        float inv = 1.f / sum;
#pragma unroll
        for (int i = 0; i < 21; i++) Bf[i * SSTR + j] = e[i] * inv + 1e-8f;
      }
      __syncthreads();
      // ---- P5b: row sums over N -> A pad[257] ----
#pragma unroll
      for (int q3 = 0; q3 < 3; q3++) {
        int i = w * 3 + q3;
        if (i < 21) {
          float s = Bf[i * SSTR + lane] + Bf[i * SSTR + lane + 64] + Bf[i * SSTR + lane + 128];
          s = wredsum(s);
          if (lane == 0) A[i * SSTR + 257] = s;  // rsum
        }
      }
      __syncthreads();
      // ---- P5c: attn = ao/rsum ; emit attn_ori on it==2 ----
      {
        float* oa = out_attn + ((size_t)(b * 16 + f)) * 4032;
        for (int idx = tid; idx < 4032; idx += 512) {
          int i = idx / 192, j = idx - i * 192;
          float ao = Bf[i * SSTR + j];
          if (it == 2) oa[idx] = ao;
          Bf[i * SSTR + j] = ao / A[i * SSTR + 257];
        }
      }
      __syncthreads();
      // ---- P6: P = attn @ lnx -> A (MFMA 2-term, K=192, N=256) ----
      {
        const int l = tid & 63, wv = tid >> 6;
        const int mt = wv & 1, dtb = (wv >> 1) * 4, lq = l >> 4, lr = l & 15;
        const int row = mt * 16 + lr;
        const bool rv = row < 21;
        const float* arow = Bf + row * SSTR;
        floatx4 acc[4] = {vzero, vzero, vzero, vzero};
        for (int ks = 0; ks < 6; ks++) {
          const int k0 = ks * 32 + lq * 8;
          half8 ahi, alo;
          if (rv) split8s(arow + k0, ahi, alo);
          else { zero8(ahi); zero8(alo); }
#pragma unroll
          for (int t = 0; t < 4; t++) {
            const int dd = (dtb + t) * 16 + lr;
            half8 bfr;
#pragma unroll
            for (int e = 0; e < 8; e++) bfr[e] = LX[dd * 193 + k0 + e];
            acc[t] = mfma16(ahi, bfr, acc[t]);
            acc[t] = mfma16(alo, bfr, acc[t]);
          }
        }
#pragma unroll
        for (int t = 0; t < 4; t++) {
          const int dd = (dtb + t) * 16 + lr;
#pragma unroll
          for (int r = 0; r < 4; r++) {
            const int i = mt * 16 + lq * 4 + r;
            if (i < 21) A[i * SSTR + dd] = acc[t][r];
          }
        }
      }
      __syncthreads();
      // ---- P7: upd = P @ Wv^T + bv -> Bf (MFMA) ----
      {
        floatx4 acc[4] = {vzero, vzero, vzero, vzero};
        mfma_gemm_acc(A, WV_OFF, tid, acc);
        mfma_gemm_store(Bf, acc, bv, false, tid);
      }
      __syncthreads();
      // ---- P8: GRU(upd=Bf, slots=SL) -> A := h (MFMA, ih/hh separate) ----
      {
        const int l = tid & 63, wv = tid >> 6;
        const int mt = wv & 1, dtb = (wv >> 1) * 4, lq = l >> 4, lr = l & 15;
        const int row = mt * 16 + lr;
        const bool rv = row < 21;
        const float* urow = Bf + row * SSTR;
        const float* srow = SL + row * SSTR;
        for (int p = 0; p < 2; p++) {
          floatx4 aih[2][3], ahh[2][3];
#pragma unroll
          for (int gi = 0; gi < 2; gi++)
#pragma unroll
            for (int g = 0; g < 3; g++) { aih[gi][g] = vzero; ahh[gi][g] = vzero; }
          for (int ks = 0; ks < 8; ks++) {
            const int k0 = ks * 32 + lq * 8;
            half8 uhi, ulo, shi, slo;
            if (rv) { split8s(urow + k0, uhi, ulo); split8s(srow + k0, shi, slo); }
            else { zero8(uhi); zero8(ulo); zero8(shi); zero8(slo); }
#pragma unroll
            for (int gi = 0; gi < 2; gi++) {
              const int dt = dtb + p * 2 + gi;
#pragma unroll
              for (int g = 0; g < 3; g++) {
                const int colI = g * 256 + dt * 16 + lr;
                const uint4* bp = g_wpk + WIH_OFF + ((colI << 5) + (ks << 2) + lq) * 2;
                union { uint4 u; half8 h; } bh, bl;
                bh.u = bp[0]; bl.u = bp[1];
                aih[gi][g] = mfma16(uhi, bh.h, aih[gi][g]);
                aih[gi][g] = mfma16(ulo, bh.h, aih[gi][g]);
                aih[gi][g] = mfma16(uhi, bl.h, aih[gi][g]);
                const uint4* bp2 = g_wpk + WHH_OFF + ((colI << 5) + (ks << 2) + lq) * 2;
                bh.u = bp2[0]; bl.u = bp2[1];
                ahh[gi][g] = mfma16(shi, bh.h, ahh[gi][g]);
                ahh[gi][g] = mfma16(slo, bh.h, ahh[gi][g]);
                ahh[gi][g] = mfma16(shi, bl.h, ahh[gi][g]);
              }
            }
          }
#pragma unroll
          for (int gi = 0; gi < 2; gi++) {
            const int dt = dtb + p * 2 + gi;
            const int dd = dt * 16 + lr;
            const float bihr = bih[dd], bihz = bih[256 + dd], bihn = bih[512 + dd];
            const float bhhr = bhh[dd], bhhz = bhh[256 + dd], bhhn = bhh[512 + dd];
#pragma unroll
            for (int r = 0; r < 4; r++) {
              const int i = mt * 16 + lq * 4 + r;
              if (i < 21) {
                float rg = fsigmoid(aih[gi][0][r] + ahh[gi][0][r] + bihr + bhhr);
                float zg = fsigmoid(aih[gi][1][r] + ahh[gi][1][r] + bihz + bhhz);
                float ng = ftanh(aih[gi][2][r] + bihn + rg * (ahh[gi][2][r] + bhhn));
                A[i * SSTR + dd] = (1.f - zg) * ng + zg * SL[i * SSTR + dd];
              }
            }
          }
        }
      }
      __syncthreads();
      // ---- P9: lnH = LN(A) -> Bf ----
#pragma unroll
      for (int rr = 0; rr < 3; rr++) {
        int row = w + rr * 8;
        if (row < 21) {
          const float* ar = A + row * SSTR + lane * 4;
          float2 xa = *(const float2*)(ar);
          float2 xb = *(const float2*)(ar + 2);
          float m = wredsum(xa.x + xa.y + xb.x + xb.y) * (1.f / 256.f);
          float d0 = xa.x - m, d1 = xa.y - m, d2 = xb.x - m, d3 = xb.y - m;
          float q2 = wredsum(d0 * d0 + d1 * d1 + d2 * d2 + d3 * d3);
          float rs = 1.f / sqrtf(q2 * (1.f / 256.f) + 1e-5f);
          int c = lane * 4;
          Bf[row * SSTR + c + 0] = d0 * rs * g_ff[c + 0] + be_ff[c + 0];
          Bf[row * SSTR + c + 1] = d1 * rs * g_ff[c + 1] + be_ff[c + 1];
          Bf[row * SSTR + c + 2] = d2 * rs * g_ff[c + 2] + be_ff[c + 2];
          Bf[row * SSTR + c + 3] = d3 * rs * g_ff[c + 3] + be_ff[c + 3];
        }
      }
      __syncthreads();
      // ---- P10: ffa = relu(lnH @ W1^T + b1) -> SL (slots dead after GRU) ----
      {
        floatx4 acc[4] = {vzero, vzero, vzero, vzero};
        mfma_gemm_acc(Bf, W1_OFF, tid, acc);
        mfma_gemm_store(SL, acc, b1, true, tid);
      }
      __syncthreads();
      // ---- P11: SL = h(A) + ffa(SL) @ W2^T + b2 ----
      {
        floatx4 acc[4] = {vzero, vzero, vzero, vzero};
        mfma_gemm_acc(SL, W2_OFF, tid, acc);
        __syncthreads();
        const int l = tid & 63, wv = tid >> 6;
        const int mt = wv & 1, ntb = (wv >> 1) * 4, lq = l >> 4, lr = l & 15;
#pragma unroll
        for (int t = 0; t < 4; t++) {
          const int col = (ntb + t) * 16 + lr;
          const float bb = b2[col];
#pragma unroll
          for (int r = 0; r < 4; r++) {
            const int i = mt * 16 + lq * 4 + r;
            if (i < 21) SL[i * SSTR + col] = A[i * SSTR + col] + acc[t][r] + bb;
          }
        }
      }
      __syncthreads();
    }
  }
  // ---- output: slots[:, :20, :] ----
  for (int i = tid; i < 20 * 256; i += 512) {
    int s = i >> 8, dd = i & 255;
    out_slots[((size_t)b * 20 + s) * 256 + dd] = SL[s * SSTR + dd];
  }
}

extern "C" void kernel_launch(void* const* d_in, const int* in_sizes, int n_in,
                              void* d_out, int out_size, void* d_ws, size_t ws_size,
                              hipStream_t stream) {
  const float* inputs = (const float*)d_in[0];
  const float* noise = (const float*)d_in[1];
  const float* mu = (const float*)d_in[2];
  const float* sigma = (const float*)d_in[3];
  const float* Wq = (const float*)d_in[4];
  const float* bq = (const float*)d_in[5];
  const float* Wk = (const float*)d_in[6];
  const float* bk = (const float*)d_in[7];
  const float* Wv = (const float*)d_in[8];
  const float* bv = (const float*)d_in[9];
  const float* W1 = (const float*)d_in[10];
  const float* b1 = (const float*)d_in[11];
  const float* W2 = (const float*)d_in[12];
  const float* b2 = (const float*)d_in[13];
  const float* Wih = (const float*)d_in[14];
  const float* bih = (const float*)d_in[15];
  const float* Whh = (const float*)d_in[16];
  const float* bhh = (const float*)d_in[17];
  const float* g_in = (const float*)d_in[18];
  const float* be_in = (const float*)d_in[19];
  const float* g_sl = (const float*)d_in[20];
  const float* be_sl = (const float*)d_in[21];
  const float* g_ff = (const float*)d_in[22];
  const float* be_ff = (const float*)d_in[23];

  float* out_slots = (float*)d_out;
  float* out_attn = out_slots + 32 * 20 * 256;

  k_prep<<<88, 1024, 0, stream>>>(Wq, Wk, Wv, W1, W2, Wih, Whh);
  k_all<<<32, 512, 0, stream>>>(inputs, noise, mu, sigma, bq, bk, bv, b1, b2,
                                bih, bhh, g_in, be_in, g_sl, be_sl, g_ff, be_ff,
                                out_slots, out_attn);
}